// Round 1
// baseline (224.853 us; speedup 1.0000x reference)
//
#include <hip/hip_runtime.h>

#define BB 32
#define NN 256
#define DD 3
#define MM 64
#define EIN 7
#define EHID 14
#define NHID 6

__device__ __forceinline__ float sigm(float x) {
    return __builtin_amdgcn_rcpf(1.0f + __expf(-x));
}

__global__ __launch_bounds__(64) void egnn_fused(
    const float* __restrict__ x,     // [B,N,3]
    const float* __restrict__ W1,    // [7,14]
    const float* __restrict__ b1,    // [14]
    const float* __restrict__ W2,    // [14,64]
    const float* __restrict__ b2,    // [64]
    const float* __restrict__ Wg,    // [64,1]
    const float* __restrict__ bg,    // [1]
    const float* __restrict__ gamma, // [3]
    const float* __restrict__ beta,  // [3]
    const float* __restrict__ Wn1,   // [67,6]
    const float* __restrict__ bn1,   // [6]
    const float* __restrict__ Wn2,   // [6,3]
    const float* __restrict__ bn2,   // [3]
    const int*   __restrict__ mask,  // [B,N]
    float* __restrict__ out)         // [B,N,3]
{
    const int bi   = blockIdx.x;     // b*N + i
    const int b    = bi >> 8;
    const int i    = bi & 255;
    const int lane = threadIdx.x;    // 0..63

    const float* xb = x + b * NN * DD;
    const float xi0 = xb[i * 3 + 0];
    const float xi1 = xb[i * 3 + 1];
    const float xi2 = xb[i * 3 + 2];
    const int   mi  = mask[b * NN + i];

    float macc[MM];
#pragma unroll
    for (int m = 0; m < MM; ++m) macc[m] = 0.0f;

    // each lane processes 4 edge targets j
    for (int jj = 0; jj < 4; ++jj) {
        const int j = jj * 64 + lane;
        const float xj0 = xb[j * 3 + 0];
        const float xj1 = xb[j * 3 + 1];
        const float xj2 = xb[j * 3 + 2];
        const int   mj  = mask[b * NN + j];

        const float r0 = xi0 - xj0, r1 = xi1 - xj1, r2 = xi2 - xj2;
        const float rd = r0 * r0 + r1 * r1 + r2 * r2;
        const float e[EIN] = {xi0, xi1, xi2, xj0, xj1, xj2, rd};

        // edge MLP layer 1: 7 -> 14, SiLU
        float h[EHID];
#pragma unroll
        for (int u = 0; u < EHID; ++u) {
            float s = b1[u];
#pragma unroll
            for (int k = 0; k < EIN; ++k) s += e[k] * W1[k * EHID + u];
            h[u] = s * sigm(s);
        }

        // edge MLP layer 2: 14 -> 64, SiLU; fused gate dot-product
        float t[MM];
        float g = bg[0];
#pragma unroll
        for (int m = 0; m < MM; ++m) {
            float s = b2[m];
#pragma unroll
            for (int k = 0; k < EHID; ++k) s += h[k] * W2[k * MM + m];
            const float v = s * sigm(s);
            t[m] = v;
            g += v * Wg[m];
        }
        g = sigm(g);
        const float gg = (mi && mj) ? g : 0.0f;
#pragma unroll
        for (int m = 0; m < MM; ++m) macc[m] += t[m] * gg;
    }

    // butterfly reduce each of the 64 channels across the 64 lanes;
    // afterwards every lane holds the full m_i vector
#pragma unroll
    for (int m = 0; m < MM; ++m) {
        float v = macc[m];
        v += __shfl_xor(v, 1, 64);
        v += __shfl_xor(v, 2, 64);
        v += __shfl_xor(v, 4, 64);
        v += __shfl_xor(v, 8, 64);
        v += __shfl_xor(v, 16, 64);
        v += __shfl_xor(v, 32, 64);
        macc[m] = v;
    }

    // node layernorm over D=3 (biased variance)
    const float mu = (xi0 + xi1 + xi2) * (1.0f / 3.0f);
    const float d0 = xi0 - mu, d1 = xi1 - mu, d2 = xi2 - mu;
    const float var = (d0 * d0 + d1 * d1 + d2 * d2) * (1.0f / 3.0f);
    const float rs = rsqrtf(var + 1e-5f);
    const float n0 = d0 * rs * gamma[0] + beta[0];
    const float n1 = d1 * rs * gamma[1] + beta[1];
    const float n2 = d2 * rs * gamma[2] + beta[2];

    // node MLP: 67 -> 6 (SiLU) -> 3, + residual (redundant on all lanes)
    float hn[NHID];
#pragma unroll
    for (int u = 0; u < NHID; ++u) {
        float s = bn1[u] + n0 * Wn1[0 * NHID + u] + n1 * Wn1[1 * NHID + u] +
                  n2 * Wn1[2 * NHID + u];
#pragma unroll
        for (int m = 0; m < MM; ++m) s += macc[m] * Wn1[(DD + m) * NHID + u];
        hn[u] = s * sigm(s);
    }

    if (lane < 3) {
        const float xres = (lane == 0) ? xi0 : ((lane == 1) ? xi1 : xi2);
        float s = bn2[lane] + xres;
#pragma unroll
        for (int u = 0; u < NHID; ++u) s += hn[u] * Wn2[u * DD + lane];
        out[bi * 3 + lane] = s;
    }
}

extern "C" void kernel_launch(void* const* d_in, const int* in_sizes, int n_in,
                              void* d_out, int out_size, void* d_ws, size_t ws_size,
                              hipStream_t stream) {
    const float* x     = (const float*)d_in[0];
    const float* W1    = (const float*)d_in[1];
    const float* b1    = (const float*)d_in[2];
    const float* W2    = (const float*)d_in[3];
    const float* b2    = (const float*)d_in[4];
    const float* Wg    = (const float*)d_in[5];
    const float* bg    = (const float*)d_in[6];
    const float* gamma = (const float*)d_in[7];
    const float* beta  = (const float*)d_in[8];
    const float* Wn1   = (const float*)d_in[9];
    const float* bn1   = (const float*)d_in[10];
    const float* Wn2   = (const float*)d_in[11];
    const float* bn2   = (const float*)d_in[12];
    const int*   mask  = (const int*)d_in[13];
    float* out = (float*)d_out;

    dim3 grid(BB * NN);
    dim3 block(64);
    hipLaunchKernelGGL(egnn_fused, grid, block, 0, stream,
                       x, W1, b1, W2, b2, Wg, bg, gamma, beta,
                       Wn1, bn1, Wn2, bn2, mask, out);
}

// Round 2
// 68.370 us; speedup vs baseline: 3.2888x; 3.2888x over previous
//
#include <hip/hip_runtime.h>

#define NN 256
#define MM 64
#define EHID 14
#define NHID 6

typedef short short8 __attribute__((ext_vector_type(8)));
typedef float f32x16 __attribute__((ext_vector_type(16)));

__device__ __forceinline__ float sigm(float x) {
    return __builtin_amdgcn_rcpf(1.0f + __expf(-x));
}
// round-to-nearest-even f32 -> bf16 bits
__device__ __forceinline__ unsigned int bfbits(float f) {
    unsigned int u = __builtin_bit_cast(unsigned int, f);
    return (u + 0x7FFFu + ((u >> 16) & 1u)) >> 16;
}

__global__ __launch_bounds__(256) void egnn_mfma(
    const float* __restrict__ x,
    const float* __restrict__ W1, const float* __restrict__ b1,
    const float* __restrict__ W2, const float* __restrict__ b2,
    const float* __restrict__ Wg, const float* __restrict__ bg,
    const float* __restrict__ gamma, const float* __restrict__ beta,
    const float* __restrict__ Wn1, const float* __restrict__ bn1,
    const float* __restrict__ Wn2, const float* __restrict__ bn2,
    const int* __restrict__ mask, float* __restrict__ out)
{
    // per-wave h staging: 256 edges x 16 bf16 (32 B) = 8 KB ; 4 waves
    __shared__ int4 hfrag[4][NN][2];
    __shared__ __align__(16) float ldsm[4][MM];

    const int tid  = threadIdx.x;
    const int wid  = tid >> 6;
    const int l    = tid & 63;
    const int l31  = l & 31;
    const int half = l >> 5;

    const int gi = blockIdx.x * 4 + wid;   // global (b,i); each wave owns one i
    const int b  = gi >> 8;
    const int i  = gi & 255;

    const float* xb = x + b * (NN * 3);
    const float xi0 = xb[i*3+0], xi1 = xb[i*3+1], xi2 = xb[i*3+2];
    const int   mi  = mask[b*NN + i];

    float macc0[16], macc1[16];
#pragma unroll
    for (int r = 0; r < 16; ++r) { macc0[r] = 0.f; macc1[r] = 0.f; }

    short8 afr0 = {0,0,0,0,0,0,0,0}, afr1 = {0,0,0,0,0,0,0,0};
    float wgv0[16], wgv1[16];

    if (mi) {
        // ---- A fragments: W2^T (rows = channel, K = 14 + bias-ch(=b2) + pad0) ----
        // assumed layout: lane holds A-row (l&31), k = 8*(l>>5)+e (e=0..7).
        // B built with the SAME k-map, so any consistent k-permutation cancels.
#pragma unroll
        for (int mf = 0; mf < 2; ++mf) {
            const int ch = l31 + 32*mf;
            unsigned int apk[4];
#pragma unroll
            for (int e2 = 0; e2 < 4; ++e2) {
                const int k0 = 8*half + 2*e2, k1 = k0 + 1;
                const float w0 = (k0 < EHID) ? W2[k0*MM + ch] : ((k0 == EHID) ? b2[ch] : 0.f);
                const float w1 = (k1 < EHID) ? W2[k1*MM + ch] : ((k1 == EHID) ? b2[ch] : 0.f);
                apk[e2] = bfbits(w0) | (bfbits(w1) << 16);
            }
            const int4 ai4 = make_int4((int)apk[0], (int)apk[1], (int)apk[2], (int)apk[3]);
            if (mf == 0) afr0 = __builtin_bit_cast(short8, ai4);
            else         afr1 = __builtin_bit_cast(short8, ai4);
        }
        // gate weights in C/D layout: row = (r&3)+8*(r>>2)+4*half  (m74/m101-verified)
#pragma unroll
        for (int r = 0; r < 16; ++r) {
            const int row = (r & 3) + 8*(r >> 2) + 4*half;
            wgv0[r] = Wg[row];
            wgv1[r] = Wg[row + 32];
        }

        // ---- layer-1 i-part hoist ----
        float Ai[EHID];
#pragma unroll
        for (int u = 0; u < EHID; ++u)
            Ai[u] = b1[u] + xi0*W1[0*EHID+u] + xi1*W1[1*EHID+u] + xi2*W1[2*EHID+u];

        // ---- Phase A: h for all 256 edges, edge-per-lane, 4 batches ----
        for (int t = 0; t < 4; ++t) {
            const int j = t*64 + l;
            const float xj0 = xb[j*3+0], xj1 = xb[j*3+1], xj2 = xb[j*3+2];
            const float r0 = xi0-xj0, r1 = xi1-xj1, r2 = xi2-xj2;
            const float rd = r0*r0 + r1*r1 + r2*r2;
            float hv[16];
#pragma unroll
            for (int u = 0; u < EHID; ++u) {
                const float p = Ai[u] + xj0*W1[3*EHID+u] + xj1*W1[4*EHID+u]
                              + xj2*W1[5*EHID+u] + rd*W1[6*EHID+u];
                hv[u] = p * sigm(p);
            }
            hv[14] = 1.0f;   // bias channel
            hv[15] = 0.0f;   // pad
            unsigned int pk[8];
#pragma unroll
            for (int e = 0; e < 8; ++e)
                pk[e] = bfbits(hv[2*e]) | (bfbits(hv[2*e+1]) << 16);
            hfrag[wid][j][0] = make_int4((int)pk[0], (int)pk[1], (int)pk[2], (int)pk[3]);
            hfrag[wid][j][1] = make_int4((int)pk[4], (int)pk[5], (int)pk[6], (int)pk[7]);
        }
    }
    __syncthreads();

    if (mi) {
        const float bg0 = bg[0];
        // ---- 8 rounds x 32 edges: 2 MFMA + SiLU + gate + gated accumulate ----
        for (int rnd = 0; rnd < 8; ++rnd) {
            const int eloc = rnd*32 + l31;                 // B col = edge
            const int4 hb = hfrag[wid][eloc][half];        // same k-map as A
            const short8 bfr = __builtin_bit_cast(short8, hb);
            f32x16 c0, c1;
#pragma unroll
            for (int r = 0; r < 16; ++r) { c0[r] = 0.f; c1[r] = 0.f; }
            c0 = __builtin_amdgcn_mfma_f32_32x32x16_bf16(afr0, bfr, c0, 0, 0, 0);
            c1 = __builtin_amdgcn_mfma_f32_32x32x16_bf16(afr1, bfr, c1, 0, 0, 0);

            const int mj = mask[b*NN + rnd*32 + l31];
            float v0[16], v1[16];
            float gp = 0.f;
#pragma unroll
            for (int r = 0; r < 16; ++r) {
                v0[r] = c0[r] * sigm(c0[r]);
                gp += v0[r] * wgv0[r];
                v1[r] = c1[r] * sigm(c1[r]);
                gp += v1[r] * wgv1[r];
            }
            const float go = __shfl_xor(gp, 32, 64);       // other channel half
            float g = sigm(gp + go + bg0);
            g = mj ? g : 0.f;
#pragma unroll
            for (int r = 0; r < 16; ++r) {
                macc0[r] += v0[r] * g;
                macc1[r] += v1[r] * g;
            }
        }
        // ---- butterfly sum over the 32 edge-columns ----
#pragma unroll
        for (int s = 1; s <= 16; s <<= 1) {
#pragma unroll
            for (int r = 0; r < 16; ++r) {
                macc0[r] += __shfl_xor(macc0[r], s, 64);
                macc1[r] += __shfl_xor(macc1[r], s, 64);
            }
        }
        if (l31 == 0) {
#pragma unroll
            for (int r = 0; r < 16; ++r) {
                const int row = (r & 3) + 8*(r >> 2) + 4*half;
                ldsm[wid][row]      = macc0[r];
                ldsm[wid][row + 32] = macc1[r];
            }
        }
    } else {
        if (l31 == 0) {
#pragma unroll
            for (int r = 0; r < 16; ++r) {
                const int row = (r & 3) + 8*(r >> 2) + 4*half;
                ldsm[wid][row]      = 0.f;
                ldsm[wid][row + 32] = 0.f;
            }
        }
    }
    __syncthreads();

    // ---- node phase (replicated across the wave's 64 lanes) ----
    const float mu  = (xi0 + xi1 + xi2) * (1.f/3.f);
    const float d0  = xi0 - mu, d1 = xi1 - mu, d2 = xi2 - mu;
    const float var = (d0*d0 + d1*d1 + d2*d2) * (1.f/3.f);
    const float rs  = rsqrtf(var + 1e-5f);
    const float n0  = d0*rs*gamma[0] + beta[0];
    const float n1  = d1*rs*gamma[1] + beta[1];
    const float n2  = d2*rs*gamma[2] + beta[2];

    float sa[NHID];
#pragma unroll
    for (int u = 0; u < NHID; ++u)
        sa[u] = bn1[u] + n0*Wn1[0*NHID+u] + n1*Wn1[1*NHID+u] + n2*Wn1[2*NHID+u];

    const float4* mv4 = (const float4*)(&ldsm[wid][0]);
#pragma unroll
    for (int c4 = 0; c4 < 16; ++c4) {
        const float4 mv = mv4[c4];
        const int ch = c4 * 4;
#pragma unroll
        for (int u = 0; u < NHID; ++u) {
            sa[u] += mv.x * Wn1[(3+ch+0)*NHID+u] + mv.y * Wn1[(3+ch+1)*NHID+u]
                   + mv.z * Wn1[(3+ch+2)*NHID+u] + mv.w * Wn1[(3+ch+3)*NHID+u];
        }
    }
    if (l < 3) {
        const float xres = (l == 0) ? xi0 : ((l == 1) ? xi1 : xi2);
        float s = bn2[l] + xres;
#pragma unroll
        for (int u = 0; u < NHID; ++u) s += sa[u] * sigm(sa[u]) * Wn2[u*3 + l];
        out[gi*3 + l] = s;
    }
}

extern "C" void kernel_launch(void* const* d_in, const int* in_sizes, int n_in,
                              void* d_out, int out_size, void* d_ws, size_t ws_size,
                              hipStream_t stream) {
    const float* x     = (const float*)d_in[0];
    const float* W1    = (const float*)d_in[1];
    const float* b1    = (const float*)d_in[2];
    const float* W2    = (const float*)d_in[3];
    const float* b2    = (const float*)d_in[4];
    const float* Wg    = (const float*)d_in[5];
    const float* bg    = (const float*)d_in[6];
    const float* gamma = (const float*)d_in[7];
    const float* beta  = (const float*)d_in[8];
    const float* Wn1   = (const float*)d_in[9];
    const float* bn1   = (const float*)d_in[10];
    const float* Wn2   = (const float*)d_in[11];
    const float* bn2   = (const float*)d_in[12];
    const int*   mask  = (const int*)d_in[13];
    float* out = (float*)d_out;

    dim3 grid((32 * NN) / 4);   // 4 waves per block, one (b,i) per wave
    dim3 block(256);
    hipLaunchKernelGGL(egnn_mfma, grid, block, 0, stream,
                       x, W1, b1, W2, b2, Wg, bg, gamma, beta,
                       Wn1, bn1, Wn2, bn2, mask, out);
}